// Round 2
// 2423.398 us; speedup vs baseline: 1.7820x; 1.7820x over previous
//
#include <hip/hip_runtime.h>
#include <cstdint>
#include <cstddef>

#define M_TOK 65536
#define DIM   640
#define LAT   2560
#define KSEL  32

typedef unsigned short u16;
using bf16x8 = __attribute__((ext_vector_type(8))) __bf16;
using f32x4  = __attribute__((ext_vector_type(4))) float;

// ---------------------------------------------------------------------------
// bf16 split helpers: x = hi + lo, both RNE bf16. Residual |x-hi-lo| <= 2^-17|x|.
// ---------------------------------------------------------------------------
__device__ __forceinline__ u16 f2b_hi(float f) {
  unsigned u = __float_as_uint(f);
  u += 0x7FFFu + ((u >> 16) & 1u);
  return (u16)(u >> 16);
}
__device__ __forceinline__ float b2f(u16 h) {
  return __uint_as_float(((unsigned)h) << 16);
}

// K_split: fp32 src -> hi/lo bf16 planes (4 floats per thread).
__global__ __launch_bounds__(256) void k_split(const float* __restrict__ src,
                                               u16* __restrict__ hi,
                                               u16* __restrict__ lo, int n4) {
  int i = blockIdx.x * 256 + threadIdx.x;
  if (i >= n4) return;
  float4 x = ((const float4*)src)[i];
  ushort4 h, l;
  h.x = f2b_hi(x.x); l.x = f2b_hi(x.x - b2f(h.x));
  h.y = f2b_hi(x.y); l.y = f2b_hi(x.y - b2f(h.y));
  h.z = f2b_hi(x.z); l.z = f2b_hi(x.z - b2f(h.z));
  h.w = f2b_hi(x.w); l.w = f2b_hi(x.w - b2f(h.w));
  ((ushort4*)hi)[i] = h;
  ((ushort4*)lo)[i] = l;
}

// ---------------------------------------------------------------------------
// K0: transpose W_dec [640][2560] -> WdT [2560][640] (unchanged).
// ---------------------------------------------------------------------------
__global__ __launch_bounds__(256) void k_transpose(const float* __restrict__ W,
                                                   float* __restrict__ WT) {
  __shared__ float tile[32][33];
  const int c0 = blockIdx.x * 32;
  const int r0 = blockIdx.y * 32;
  const int tx = threadIdx.x & 31;
  const int ty = threadIdx.x >> 5;
#pragma unroll
  for (int i = 0; i < 32; i += 8) {
    tile[ty + i][tx] = W[(r0 + ty + i) * LAT + c0 + tx];
  }
  __syncthreads();
#pragma unroll
  for (int i = 0; i < 32; i += 8) {
    WT[(c0 + ty + i) * DIM + r0 + tx] = tile[tx][ty + i];
  }
}

// ---------------------------------------------------------------------------
// K1: encode via bf16 MFMA, 3-product fp32-split (unchanged from round 1):
//   Lat = Xh*Wh^T + Xh*Wl^T + Xl*Wh^T + b_enc  (fp32 accumulate)
// ---------------------------------------------------------------------------
typedef __attribute__((address_space(1))) const unsigned int gu32;
typedef __attribute__((address_space(3))) unsigned int lu32;

__device__ __forceinline__ void gld16(const u16* g, u16* l) {
  __builtin_amdgcn_global_load_lds((gu32*)g, (lu32*)l, 16, 0, 0);
}

__global__ __launch_bounds__(256, 3) void k_encode(
    const u16* __restrict__ Xh, const u16* __restrict__ Xl,
    const u16* __restrict__ Wh, const u16* __restrict__ Wl,
    const float* __restrict__ be, float* __restrict__ Lat) {
  __shared__ __align__(16) u16 sAh[128][32];
  __shared__ __align__(16) u16 sAl[128][32];
  __shared__ __align__(16) u16 sBh[128][32];
  __shared__ __align__(16) u16 sBl[128][32];

  const int tid = threadIdx.x;
  const int bn0 = blockIdx.x * 128;  // over LAT (20)
  const int bm0 = blockIdx.y * 128;  // over M (512)
  const int ln  = tid & 63;
  const int wv  = tid >> 6;
  const int wm  = (wv >> 1) * 64;
  const int wn  = (wv & 1) * 64;
  const int fr  = ln & 15;
  const int fq  = ln >> 4;

  // staging map: byte offset == tid*16 -> wave-uniform base + lane*16 (linear)
  const int r0 = tid >> 2;
  const int r1 = 64 + r0;
  const int k8 = (tid & 3) * 8;

  f32x4 acc[4][4];
#pragma unroll
  for (int i = 0; i < 4; ++i)
#pragma unroll
    for (int j = 0; j < 4; ++j) acc[i][j] = (f32x4){0.f, 0.f, 0.f, 0.f};

  const size_t gA0 = (size_t)(bm0 + r0) * DIM + k8;
  const size_t gA1 = (size_t)(bm0 + r1) * DIM + k8;
  const size_t gB0 = (size_t)(bn0 + r0) * DIM + k8;
  const size_t gB1 = (size_t)(bn0 + r1) * DIM + k8;

  for (int kb = 0; kb < DIM; kb += 32) {
    gld16(Xh + gA0 + kb, &sAh[r0][k8]);
    gld16(Xh + gA1 + kb, &sAh[r1][k8]);
    gld16(Xl + gA0 + kb, &sAl[r0][k8]);
    gld16(Xl + gA1 + kb, &sAl[r1][k8]);
    gld16(Wh + gB0 + kb, &sBh[r0][k8]);
    gld16(Wh + gB1 + kb, &sBh[r1][k8]);
    gld16(Wl + gB0 + kb, &sBl[r0][k8]);
    gld16(Wl + gB1 + kb, &sBl[r1][k8]);
    __syncthreads();  // compiler drains vmcnt before barrier

    bf16x8 ah[4], al[4], bh[4], bl[4];
#pragma unroll
    for (int mr = 0; mr < 4; ++mr) {
      ah[mr] = *(const bf16x8*)&sAh[wm + mr * 16 + fr][fq * 8];
      al[mr] = *(const bf16x8*)&sAl[wm + mr * 16 + fr][fq * 8];
    }
#pragma unroll
    for (int nr = 0; nr < 4; ++nr) {
      bh[nr] = *(const bf16x8*)&sBh[wn + nr * 16 + fr][fq * 8];
      bl[nr] = *(const bf16x8*)&sBl[wn + nr * 16 + fr][fq * 8];
    }
#pragma unroll
    for (int mr = 0; mr < 4; ++mr)
#pragma unroll
      for (int nr = 0; nr < 4; ++nr) {
        acc[mr][nr] = __builtin_amdgcn_mfma_f32_16x16x32_bf16(
            ah[mr], bh[nr], acc[mr][nr], 0, 0, 0);
        acc[mr][nr] = __builtin_amdgcn_mfma_f32_16x16x32_bf16(
            ah[mr], bl[nr], acc[mr][nr], 0, 0, 0);
        acc[mr][nr] = __builtin_amdgcn_mfma_f32_16x16x32_bf16(
            al[mr], bh[nr], acc[mr][nr], 0, 0, 0);
      }
    __syncthreads();
  }

  // epilogue: D row = m*16 + fq*4 + j, col = n*16 + fr  (verified layout)
#pragma unroll
  for (int nr = 0; nr < 4; ++nr) {
    const int col = bn0 + wn + nr * 16 + fr;
    const float bias = be[col];
#pragma unroll
    for (int mr = 0; mr < 4; ++mr) {
      const int rowb = bm0 + wm + mr * 16 + fq * 4;
#pragma unroll
      for (int j = 0; j < 4; ++j) {
        Lat[(size_t)(rowb + j) * LAT + col] = acc[mr][nr][j] + bias;
      }
    }
  }
}

// ---------------------------------------------------------------------------
// K2: per-row exact top-32.
//  - candidates by guarded threshold on approx latents
//  - fast path: if no competitor within EPS of the rank-31 value, approx
//    order is provably exact (EPS >> 20x the split-GEMM error bound)
//  - slow path: recompute ALL approx-ranks [0,B) with a sequential fp32
//    fma chain (round-0's proven accumulation order, no forced prefix),
//    sort by (exact desc, idx asc), take 32.
// ---------------------------------------------------------------------------
__device__ __forceinline__ unsigned int ordf(float f) {
  unsigned int u = __float_as_uint(f);
  return (u & 0x80000000u) ? ~u : (u | 0x80000000u);
}
__device__ __forceinline__ float iordf(unsigned int o) {
  unsigned int u = (o & 0x80000000u) ? (o ^ 0x80000000u) : ~o;
  return __uint_as_float(u);
}
__device__ __forceinline__ void keydec(unsigned long long c, float* v, int* idx) {
  unsigned long long key = ~c;
  *v = iordf((unsigned int)(key >> 12));
  *idx = 4095 - (int)(key & 0xFFFULL);
}

#define EPS_SEL 4e-4f   // >> worst-case split-GEMM error (~1e-5)
#define T_GUARD 1e-3f   // rung-threshold guard
#define WINCAP  256     // one refined candidate per thread

__global__ __launch_bounds__(256) void k_topk(
    float* __restrict__ Lat, const float* __restrict__ X,
    const float* __restrict__ We, const float* __restrict__ be,
    float* __restrict__ topv, int* __restrict__ topi) {
  const int row = blockIdx.x;
  const int tid = threadIdx.x;
  float* Rp = Lat + (size_t)row * LAT;

  __shared__ unsigned long long cand[4096];  // 32 KB; reused as out-row later
  __shared__ float s_red[8];
  __shared__ int s_cnt;
  __shared__ float s_stats[2];
  __shared__ int s_selIdx[KSEL];
  __shared__ float s_selVal[KSEL];
  __shared__ int s_B;
  __shared__ float s_v31;

  // load row (10 values/thread, coalesced) + moments
  float v[10];
  float s = 0.f, ss = 0.f;
#pragma unroll
  for (int j = 0; j < 10; ++j) {
    v[j] = Rp[tid + j * 256];
    s += v[j];
    ss += v[j] * v[j];
  }
#pragma unroll
  for (int off = 32; off > 0; off >>= 1) {
    s += __shfl_down(s, off);
    ss += __shfl_down(ss, off);
  }
  const int wave = tid >> 6, lane = tid & 63;
  if (lane == 0) {
    s_red[wave] = s;
    s_red[4 + wave] = ss;
  }
  __syncthreads();
  if (tid == 0) {
    float S = s_red[0] + s_red[1] + s_red[2] + s_red[3];
    float SS = s_red[4] + s_red[5] + s_red[6] + s_red[7];
    float mean = S * (1.f / LAT);
    float var = SS * (1.f / LAT) - mean * mean;
    s_stats[0] = mean;
    s_stats[1] = sqrtf(fmaxf(var, 0.f));
  }
  __syncthreads();
  const float mean = s_stats[0], sig = s_stats[1];

  for (int rung = 0; rung < 3; ++rung) {
    const float t = (rung == 0) ? (mean + 2.0f * sig - T_GUARD)
                  : (rung == 1) ? (mean + 1.0f * sig - T_GUARD)
                                : -3.4e38f;
    __syncthreads();
    if (tid == 0) s_cnt = 0;
    __syncthreads();
    // ballot-compacted candidate build
#pragma unroll
    for (int j = 0; j < 10; ++j) {
      bool pred = v[j] > t;
      unsigned long long mask = __ballot(pred);
      int nset = __popcll(mask);
      int base = 0;
      if (lane == 0 && nset) base = atomicAdd(&s_cnt, nset);
      base = __shfl(base, 0);
      if (pred) {
        int off = __popcll(mask & ((1ULL << lane) - 1ULL));
        int idx = tid + j * 256;
        unsigned long long key =
            ((unsigned long long)ordf(v[j]) << 12) | (unsigned long long)(4095 - idx);
        cand[base + off] = ~key;  // ascending sort == val desc, idx asc
      }
    }
    __syncthreads();
    const int cnt = s_cnt;
    if (rung < 2 && cnt < KSEL + 8) continue;  // need margin below rank 31

    // pad to pow2 + bitonic sort ascending (inverted keys)
    int P = 64;
    while (P < cnt) P <<= 1;  // <= 4096
    for (int i = cnt + tid; i < P; i += 256) cand[i] = ~0ULL;
    __syncthreads();
    for (int k = 2; k <= P; k <<= 1) {
      for (int j2 = k >> 1; j2 > 0; j2 >>= 1) {
        for (int i = tid; i < P; i += 256) {
          int ixj = i ^ j2;
          if (ixj > i) {
            unsigned long long a = cand[i], b = cand[ixj];
            bool up = ((i & k) == 0);
            if ((a > b) == up) { cand[i] = b; cand[ixj] = a; }
          }
        }
        __syncthreads();
      }
    }

    if (tid == 0) {
      float vv; int ii;
      keydec(cand[KSEL - 1], &vv, &ii);
      s_v31 = vv;
      s_B = 0;
    }
    __syncthreads();
    const float v31 = s_v31;
    // if the boundary window could include unseen (below-threshold) values,
    // descend a rung to pull them into the candidate set
    if (rung < 2 && !(v31 - EPS_SEL > t)) continue;

    for (int i = tid; i < cnt; i += 256) {
      float vv; int ii;
      keydec(cand[i], &vv, &ii);
      if (vv >= v31 - EPS_SEL) atomicAdd(&s_B, 1);
    }
    __syncthreads();
    const int B = s_B;  // 32 <= B (ranks 0..31 always qualify)

    if (B != KSEL) {
      // slow path: exact fp32 recompute of approx-ranks [0, Wn), no prefix.
      // Sequential fmaf chain over k = 0..639 (round-0 accumulation order),
      // one candidate per thread; all true top-32 are in [0, B) since
      // ranks >= B have exact < v31 - EPS + err < any rank-0..31 exact.
      const int Wn = (B < WINCAP) ? B : WINCAP;
      float exv = 0.f;
      int exi = 0;
      if (tid < Wn) {
        float va;
        keydec(cand[tid], &va, &exi);
        const float* xr = X + (size_t)row * DIM;
        const float* wr = We + (size_t)exi * DIM;
        float t0 = 0.f;
        for (int k = 0; k < DIM; ++k) t0 = fmaf(xr[k], wr[k], t0);
        exv = t0 + be[exi];
      }
      __syncthreads();  // everyone done reading their cand slot
      int P2 = 64;
      while (P2 < Wn) P2 <<= 1;  // <= 256
      if (tid < Wn) {
        unsigned long long key = ((unsigned long long)ordf(exv) << 12) |
                                 (unsigned long long)(4095 - exi);
        cand[tid] = ~key;
      } else if (tid < P2) {
        cand[tid] = ~0ULL;
      }
      __syncthreads();
      for (int k = 2; k <= P2; k <<= 1) {
        for (int j2 = k >> 1; j2 > 0; j2 >>= 1) {
          if (tid < P2) {
            int i = tid, ixj = tid ^ j2;
            if (ixj > i) {
              unsigned long long a = cand[i], b = cand[ixj];
              bool up = ((i & k) == 0);
              if ((a > b) == up) { cand[i] = b; cand[ixj] = a; }
            }
          }
          __syncthreads();
        }
      }
    }

    // top-32 (fast path: approx keys; slow path: exact keys)
    if (tid < KSEL) {
      float vv; int ii;
      keydec(cand[tid], &vv, &ii);
      s_selIdx[tid] = ii;
      s_selVal[tid] = vv;
    }
    break;
  }
  __syncthreads();

  if (tid < KSEL) {
    topv[row * KSEL + tid] = s_selVal[tid];
    topi[row * KSEL + tid] = s_selIdx[tid];
  }
  __syncthreads();

  // sparsify row in place: zeros + 32 selected values
  float* outrow = (float*)cand;
#pragma unroll
  for (int j = 0; j < 10; ++j) outrow[tid + j * 256] = 0.f;
  __syncthreads();
  if (tid < KSEL) outrow[s_selIdx[tid]] = s_selVal[tid];
  __syncthreads();
#pragma unroll
  for (int j = 0; j < 10; ++j) Rp[tid + j * 256] = outrow[tid + j * 256];
}

// ---------------------------------------------------------------------------
// K3: decode (unchanged).
// ---------------------------------------------------------------------------
__global__ __launch_bounds__(256) void k_decode(const float* __restrict__ topv,
                                                const int* __restrict__ topi,
                                                const float* __restrict__ WdT,
                                                const float* __restrict__ bd,
                                                float* __restrict__ recon) {
  const int rb = blockIdx.x;
  const int tid = threadIdx.x;
  __shared__ float sv[8][KSEL];
  __shared__ int si[8][KSEL];
  {
    int r = tid >> 5, j = tid & 31;
    sv[r][j] = topv[(rb * 8 + r) * KSEL + j];
    si[r][j] = topi[(rb * 8 + r) * KSEL + j];
  }
  __syncthreads();
  const float4* W4 = (const float4*)WdT;
  const float4* b4 = (const float4*)bd;
  float4* out4 = (float4*)recon;
#pragma unroll
  for (int it = 0; it < 5; ++it) {
    int flat = it * 256 + tid;
    int r = flat / 160, d = flat - r * 160;
    float4 acc = b4[d];
#pragma unroll
    for (int j = 0; j < KSEL; ++j) {
      float sc = sv[r][j];
      float4 w = W4[(size_t)si[r][j] * 160 + d];
      acc.x += sc * w.x;
      acc.y += sc * w.y;
      acc.z += sc * w.z;
      acc.w += sc * w.w;
    }
    out4[(size_t)(rb * 8 + r) * 160 + d] = acc;
  }
}

// ---------------------------------------------------------------------------
extern "C" void kernel_launch(void* const* d_in, const int* in_sizes, int n_in,
                              void* d_out, int out_size, void* d_ws, size_t ws_size,
                              hipStream_t stream) {
  const float* x     = (const float*)d_in[0];
  const float* W_enc = (const float*)d_in[1];
  const float* b_enc = (const float*)d_in[2];
  const float* W_dec = (const float*)d_in[3];
  const float* b_dec = (const float*)d_in[4];

  float* out    = (float*)d_out;
  float* recon  = out;                          // 65536*640
  float* sparse = out + (size_t)M_TOK * DIM;    // 65536*2560 (approx latents)

  float* WdT  = (float*)d_ws;                   // 2560*640 f32
  float* topv = WdT + (size_t)LAT * DIM;        // 65536*32 f32
  int*   topi = (int*)(topv + (size_t)M_TOK * KSEL);

  // bf16 split planes:
  //  - Xh/Xl exactly fill the recon region (dead until k_decode)
  //  - Wh/Wl alias the topv region (dead until k_topk writes it)
  u16* Xh = (u16*)recon;
  u16* Xl = Xh + (size_t)M_TOK * DIM;
  u16* Wh = (u16*)topv;
  u16* Wl = Wh + (size_t)LAT * DIM;

  k_split<<<(M_TOK * DIM / 4 + 255) / 256, 256, 0, stream>>>(x, Xh, Xl, M_TOK * DIM / 4);
  k_split<<<(LAT * DIM / 4 + 255) / 256, 256, 0, stream>>>(W_enc, Wh, Wl, LAT * DIM / 4);
  k_transpose<<<dim3(LAT / 32, DIM / 32), 256, 0, stream>>>(W_dec, WdT);
  k_encode<<<dim3(LAT / 128, M_TOK / 128), 256, 0, stream>>>(Xh, Xl, Wh, Wl, b_enc, sparse);
  k_topk<<<M_TOK, 256, 0, stream>>>(sparse, x, W_enc, b_enc, topv, topi);
  k_decode<<<M_TOK / 8, 256, 0, stream>>>(topv, topi, WdT, b_dec, recon);
}